// Round 4
// baseline (752.952 us; speedup 1.0000x reference)
//
#include <hip/hip_runtime.h>

// RGCNConv basis-decomposed, sort-based aggregation + pipelined bf16 MFMA GEMM.
//   Abf = [seg_sum(bf16(x)[src] by (dst,rel)) | bf16(x)]  (bf16, [N][2304])
//   out = Abf @ WcatT^T + bias                            (f32 out)

#define N_NODES 20000
#define N_EDGES 640000
#define IN_DIM  256
#define OUT_DIM 800
#define NREL    8
#define NSEG    160000          // N_NODES * NREL
#define KS      2048            // NREL * IN_DIM
#define KTOT    2304            // KS + IN_DIM
#define NPAD    1024            // padded N for GEMM B
#define NB      625             // NSEG / 256 scan blocks

// GEMM geometry: 128x256 tile, BK=32, 8 waves (2Mx4N, 64x64), dbuf LDS 48KB
#define BM 128
#define BN 256
#define BK 32
#define NKT (KTOT / BK)         // 72
#define MT  157                 // ceil(20000/128)
#define NT  4                   // 1024/256
#define NWG (MT * NT)           // 628
#define LDSBUF 24576            // (128+256)*32*2 bytes per buffer

typedef float f32x4_t __attribute__((ext_vector_type(4)));
typedef short short8_t __attribute__((ext_vector_type(8)));

__device__ __forceinline__ unsigned short f2bf(float f) {
  unsigned u = __float_as_uint(f);
  u += 0x7fffu + ((u >> 16) & 1u);
  return (unsigned short)(u >> 16);
}

__device__ __forceinline__ float bflo(unsigned w) { return __uint_as_float(w << 16); }
__device__ __forceinline__ float bfhi(unsigned w) { return __uint_as_float(w & 0xffff0000u); }

__device__ __forceinline__ void gload16(const void* g, void* l) {
  __builtin_amdgcn_global_load_lds(
      (const __attribute__((address_space(1))) void*)g,
      (__attribute__((address_space(3))) void*)l, 16, 0, 0);
}

// ---------------- sort pipeline ----------------

__global__ void zero_counts_kernel(int* __restrict__ cnt) {
  cnt[blockIdx.x * 256 + threadIdx.x] = 0;
}

__global__ void hist_kernel(const int* __restrict__ ei, const int* __restrict__ et,
                            int* __restrict__ cnt) {
  const int e = blockIdx.x * 256 + threadIdx.x;
  const int seg = ei[N_EDGES + e] * NREL + et[e];
  atomicAdd(&cnt[seg], 1);
}

__global__ void scan_reduce_kernel(const int* __restrict__ cnt, int* __restrict__ bsum) {
  __shared__ int sm[256];
  const int t = threadIdx.x;
  sm[t] = cnt[blockIdx.x * 256 + t];
  __syncthreads();
  for (int s = 128; s > 0; s >>= 1) {
    if (t < s) sm[t] += sm[t + s];
    __syncthreads();
  }
  if (t == 0) bsum[blockIdx.x] = sm[0];
}

__global__ void scan_bsum_kernel(int* __restrict__ bsum) {
  __shared__ int sm[1024];
  const int t = threadIdx.x;
  const int v = (t < NB) ? bsum[t] : 0;
  sm[t] = v;
  __syncthreads();
  for (int s = 1; s < 1024; s <<= 1) {
    const int a = (t >= s) ? sm[t - s] : 0;
    __syncthreads();
    sm[t] += a;
    __syncthreads();
  }
  if (t < NB) bsum[t] = sm[t] - v;   // exclusive
}

__global__ void scan_final_kernel(const int* __restrict__ cnt, const int* __restrict__ bsum,
                                  int* __restrict__ off, int* __restrict__ cur) {
  __shared__ int sm[256];
  const int t = threadIdx.x;
  const int g = blockIdx.x * 256 + t;
  const int v = cnt[g];
  sm[t] = v;
  __syncthreads();
  for (int s = 1; s < 256; s <<= 1) {
    const int a = (t >= s) ? sm[t - s] : 0;
    __syncthreads();
    sm[t] += a;
    __syncthreads();
  }
  const int ex = sm[t] - v + bsum[blockIdx.x];
  off[g] = ex;
  cur[g] = ex;
}

__global__ void reorder_kernel(const int* __restrict__ ei, const int* __restrict__ et,
                               int* __restrict__ cur, int* __restrict__ sorted_src) {
  const int e = blockIdx.x * 256 + threadIdx.x;
  const int seg = ei[N_EDGES + e] * NREL + et[e];
  const int pos = atomicAdd(&cur[seg], 1);
  sorted_src[pos] = ei[e];
}

// Fill Abf[:, 2048:2304] = bf16(x).  MUST run before aggregate (it gathers these).
__global__ void xcast_kernel(const float* __restrict__ x, unsigned short* __restrict__ abf) {
  const int id = blockIdx.x * 256 + threadIdx.x;   // 20000*64
  const int row = id >> 6, lane = id & 63;
  const float4 v = ((const float4*)x)[(size_t)row * 64 + lane];
  union { unsigned short u[4]; uint2 q; } pk;
  pk.u[0] = f2bf(v.x); pk.u[1] = f2bf(v.y);
  pk.u[2] = f2bf(v.z); pk.u[3] = f2bf(v.w);
  *(uint2*)(abf + (size_t)row * KTOT + KS + lane * 4) = pk.q;
}

// One wave per segment: gather bf16 x rows from Abf x-cols (8B/lane),
// f32-accumulate, write bf16 into Abf s-part.
__global__ void aggregate_kernel(const int* __restrict__ cnt, const int* __restrict__ off,
                                 const int* __restrict__ sorted_src,
                                 unsigned short* __restrict__ abf) {
  const int seg = __builtin_amdgcn_readfirstlane(blockIdx.x * 4 + (threadIdx.x >> 6));
  const int lane = threadIdx.x & 63;
  const int ne = cnt[seg];
  const int o  = off[seg];
  float a0 = 0.f, a1 = 0.f, a2 = 0.f, a3 = 0.f;
  float b0 = 0.f, b1 = 0.f, b2 = 0.f, b3 = 0.f;
  int j = 0;
  for (; j + 1 < ne; j += 2) {
    const int s0 = sorted_src[o + j];
    const int s1 = sorted_src[o + j + 1];
    const uint2 u0 = *(const uint2*)(abf + (size_t)s0 * KTOT + KS + lane * 4);
    const uint2 u1 = *(const uint2*)(abf + (size_t)s1 * KTOT + KS + lane * 4);
    a0 += bflo(u0.x); a1 += bfhi(u0.x); a2 += bflo(u0.y); a3 += bfhi(u0.y);
    b0 += bflo(u1.x); b1 += bfhi(u1.x); b2 += bflo(u1.y); b3 += bfhi(u1.y);
  }
  if (j < ne) {
    const uint2 u0 = *(const uint2*)(abf + (size_t)sorted_src[o + j] * KTOT + KS + lane * 4);
    a0 += bflo(u0.x); a1 += bfhi(u0.x); a2 += bflo(u0.y); a3 += bfhi(u0.y);
  }
  a0 += b0; a1 += b1; a2 += b2; a3 += b3;
  const int node = seg >> 3, r = seg & 7;
  union { unsigned short u[4]; uint2 q; } pk;
  pk.u[0] = f2bf(a0); pk.u[1] = f2bf(a1);
  pk.u[2] = f2bf(a2); pk.u[3] = f2bf(a3);
  *(uint2*)(abf + (size_t)node * KTOT + r * IN_DIM + lane * 4) = pk.q;
}

// WcatT[n][k], n in [0,1024), k in [0,2304). n >= 800 zero-padded.
__global__ void build_wcat_kernel(const float* __restrict__ bases,
                                  const float* __restrict__ att,
                                  const float* __restrict__ root,
                                  unsigned short* __restrict__ wcatT) {
  const int k = blockIdx.x;
  const int n = blockIdx.y * 128 + threadIdx.x;
  float v = 0.f;
  if (n < OUT_DIM) {
    if (k < KS) {
      const int r = k >> 8, i = k & 255;
      #pragma unroll
      for (int b = 0; b < 8; ++b)
        v += att[r * 8 + b] * bases[((size_t)b * IN_DIM + i) * OUT_DIM + n];
    } else {
      v = root[(size_t)(k - KS) * OUT_DIM + n];
    }
  }
  wcatT[(size_t)n * KTOT + k] = f2bf(v);
}

// C[20000][800] = Abf[20000][2304] @ WcatT^T + bias.
// 128x256 tile, BK=32, 8 waves (2Mx4N, 64x64 each), double-buffered 48KB LDS
// (3 blocks/CU), global_load_lds staging, counted vmcnt(3), bijective XCD
// swizzle.  64B LDS rows -> ds_read_b128 is naturally bank-optimal, no swizzle.
__global__ __launch_bounds__(512, 6) void gemm_kernel(
    const unsigned short* __restrict__ abf,
    const unsigned short* __restrict__ wcatT,
    const float* __restrict__ bias, float* __restrict__ out) {
  __shared__ __align__(16) char lds[2 * LDSBUF];   // [buf][A 8K | B 16K]

  // T1: bijective XCD-chunk swizzle (m204); rows fastest within a chunk.
  const int lin = blockIdx.x;
  const int q8 = NWG >> 3, r8 = NWG & 7;           // 78, 4
  const int xcd = lin & 7, idx = lin >> 3;
  const int wg = (xcd < r8 ? xcd * (q8 + 1) : r8 * (q8 + 1) + (xcd - r8) * q8) + idx;
  const int row0 = (wg % MT) * BM;
  const int col0 = (wg / MT) * BN;

  const int tid = threadIdx.x;
  const int w = tid >> 6, l = tid & 63;
  const int wm = w >> 2, wn = w & 3;               // wave tile: rows wm*64, cols wn*64
  const int la = l & 15, lg = l >> 4;

  // staging: thread t -> row t>>2 (0..127), 8-elem k-chunk t&3
  const int srow = tid >> 2;
  const int skoff = (tid & 3) * 8;
  int ra = row0 + srow;
  ra = (ra < N_NODES) ? ra : (N_NODES - 1);        // clamp: garbage rows never stored
  const unsigned short* gA  = abf   + (size_t)ra * KTOT + skoff;
  const unsigned short* gB0 = wcatT + (size_t)(col0 + srow) * KTOT + skoff;
  const unsigned short* gB1 = wcatT + (size_t)(col0 + 128 + srow) * KTOT + skoff;

  f32x4_t acc[4][4];
  #pragma unroll
  for (int i = 0; i < 4; ++i)
    #pragma unroll
    for (int j = 0; j < 4; ++j)
      acc[i][j] = (f32x4_t)(0.0f);

  const bool wactive = (col0 + wn * 64) < OUT_DIM;  // last col tile: waves wn>=1 idle

  auto stage = [&](int buf, int kt) {
    char* base = lds + buf * LDSBUF + w * 1024;
    const int ko = kt * BK;
    gload16(gA  + ko, base);                       // A rows
    gload16(gB0 + ko, base + 8192);                // B rows 0..127
    gload16(gB1 + ko, base + 16384);               // B rows 128..255
  };

  int cur = 0;
  stage(0, 0);
  for (int kt = 0; kt < NKT; ++kt) {
    if (kt + 1 < NKT) {
      stage(cur ^ 1, kt + 1);                      // next tile's 3 loads in flight
      asm volatile("s_waitcnt vmcnt(3)" ::: "memory");   // T4: counted, not 0
    } else {
      asm volatile("s_waitcnt vmcnt(0)" ::: "memory");
    }
    __builtin_amdgcn_sched_barrier(0);
    __builtin_amdgcn_s_barrier();                  // buf[cur] staged for all waves
    __builtin_amdgcn_sched_barrier(0);

    if (wactive) {
      const char* Ab = lds + cur * LDSBUF;
      const char* Bb = Ab + 8192;
      short8_t af[4], bf[4];
      #pragma unroll
      for (int f = 0; f < 4; ++f) {
        const int rr = wm * 64 + f * 16 + la;
        af[f] = *(const short8_t*)(Ab + rr * 64 + lg * 16);
      }
      #pragma unroll
      for (int nf = 0; nf < 4; ++nf) {
        const int rr = wn * 64 + nf * 16 + la;
        bf[nf] = *(const short8_t*)(Bb + rr * 64 + lg * 16);
      }
      #pragma unroll
      for (int f = 0; f < 4; ++f)
        #pragma unroll
        for (int nf = 0; nf < 4; ++nf)
          acc[f][nf] = __builtin_amdgcn_mfma_f32_16x16x32_bf16(
              af[f], bf[nf], acc[f][nf], 0, 0, 0);
    }
    asm volatile("s_waitcnt lgkmcnt(0)" ::: "memory");   // my ds_reads done
    __builtin_amdgcn_sched_barrier(0);
    __builtin_amdgcn_s_barrier();                  // safe to overwrite buf[cur]
    __builtin_amdgcn_sched_barrier(0);
    cur ^= 1;
  }

  if (wactive) {
    #pragma unroll
    for (int nf = 0; nf < 4; ++nf) {
      const int gcol = col0 + wn * 64 + nf * 16 + la;
      if (gcol < OUT_DIM) {
        const float bv = bias[gcol];
        #pragma unroll
        for (int f = 0; f < 4; ++f) {
          const int gr0 = row0 + wm * 64 + f * 16 + lg * 4;
          #pragma unroll
          for (int j = 0; j < 4; ++j) {
            const int gr = gr0 + j;
            if (gr < N_NODES)
              out[(size_t)gr * OUT_DIM + gcol] = acc[f][nf][j] + bv;
          }
        }
      }
    }
  }
}

extern "C" void kernel_launch(void* const* d_in, const int* in_sizes, int n_in,
                              void* d_out, int out_size, void* d_ws, size_t ws_size,
                              hipStream_t stream) {
  const float* x     = (const float*)d_in[0];
  const int*   ei    = (const int*)d_in[1];
  const int*   et    = (const int*)d_in[2];
  const float* bases = (const float*)d_in[3];
  const float* att   = (const float*)d_in[4];
  const float* root  = (const float*)d_in[5];
  const float* bias  = (const float*)d_in[6];
  float* out = (float*)d_out;

  char* p = (char*)d_ws;
  unsigned short* abf   = (unsigned short*)p;  p += (size_t)N_NODES * KTOT * 2;  // 92,160,000
  unsigned short* wcatT = (unsigned short*)p;  p += (size_t)NPAD * KTOT * 2;     //  4,718,592
  int* cnt        = (int*)p;                   p += (size_t)NSEG * 4;
  int* off        = (int*)p;                   p += (size_t)NSEG * 4;
  int* cur        = (int*)p;                   p += (size_t)NSEG * 4;
  int* sorted_src = (int*)p;                   p += (size_t)N_EDGES * 4;
  int* bsum       = (int*)p;                   p += 4096;

  zero_counts_kernel<<<NB, 256, 0, stream>>>(cnt);
  hist_kernel<<<N_EDGES / 256, 256, 0, stream>>>(ei, et, cnt);
  scan_reduce_kernel<<<NB, 256, 0, stream>>>(cnt, bsum);
  scan_bsum_kernel<<<1, 1024, 0, stream>>>(bsum);
  scan_final_kernel<<<NB, 256, 0, stream>>>(cnt, bsum, off, cur);
  reorder_kernel<<<N_EDGES / 256, 256, 0, stream>>>(ei, et, cur, sorted_src);
  xcast_kernel<<<N_NODES * 64 / 256, 256, 0, stream>>>(x, abf);     // before aggregate!
  aggregate_kernel<<<NSEG / 4, 256, 0, stream>>>(cnt, off, sorted_src, abf);
  build_wcat_kernel<<<dim3(KTOT, 8), 128, 0, stream>>>(bases, att, root, wcatT);
  gemm_kernel<<<NWG, 512, 0, stream>>>(abf, wcatT, bias, out);
}

// Round 5
// 303.022 us; speedup vs baseline: 2.4848x; 2.4848x over previous
//
#include <hip/hip_runtime.h>

// RGCNConv basis-decomposed, sort-based aggregation + m97-structure bf16 MFMA GEMM.
//   Abf = [seg_sum(bf16(x)[src] by (dst,rel)) | bf16(x)]  (bf16, [N][2304])
//   out = Abf @ WcatT^T + bias                            (f32 out)

#define N_NODES 20000
#define N_EDGES 640000
#define IN_DIM  256
#define OUT_DIM 800
#define NREL    8
#define NSEG    160000          // N_NODES * NREL
#define KS      2048            // NREL * IN_DIM
#define KTOT    2304            // KS + IN_DIM
#define NPAD    896             // padded N for GEMM B (7 x 128)
#define NB      625             // NSEG / 256 scan blocks

// GEMM geometry: 128x128 tile, BK=64, 4 waves (2x2, 64x64), single 32KB LDS
#define BM 128
#define BN 128
#define BK 64
#define NKT (KTOT / BK)         // 36
#define MT  157                 // ceil(20000/128)
#define NT  7                   // 896/128
#define NWG (MT * NT)           // 1099

typedef float f32x4_t __attribute__((ext_vector_type(4)));
typedef short short8_t __attribute__((ext_vector_type(8)));

__device__ __forceinline__ unsigned short f2bf(float f) {
  unsigned u = __float_as_uint(f);
  u += 0x7fffu + ((u >> 16) & 1u);
  return (unsigned short)(u >> 16);
}

__device__ __forceinline__ float bflo(unsigned w) { return __uint_as_float(w << 16); }
__device__ __forceinline__ float bfhi(unsigned w) { return __uint_as_float(w & 0xffff0000u); }

__device__ __forceinline__ void gload16(const void* g, void* l) {
  __builtin_amdgcn_global_load_lds(
      (const __attribute__((address_space(1))) void*)g,
      (__attribute__((address_space(3))) void*)l, 16, 0, 0);
}

// ---------------- sort pipeline ----------------

__global__ void zero_counts_kernel(int* __restrict__ cnt) {
  cnt[blockIdx.x * 256 + threadIdx.x] = 0;
}

__global__ void hist_kernel(const int* __restrict__ ei, const int* __restrict__ et,
                            int* __restrict__ cnt) {
  const int e = blockIdx.x * 256 + threadIdx.x;
  const int seg = ei[N_EDGES + e] * NREL + et[e];
  atomicAdd(&cnt[seg], 1);
}

__global__ void scan_reduce_kernel(const int* __restrict__ cnt, int* __restrict__ bsum) {
  __shared__ int sm[256];
  const int t = threadIdx.x;
  sm[t] = cnt[blockIdx.x * 256 + t];
  __syncthreads();
  for (int s = 128; s > 0; s >>= 1) {
    if (t < s) sm[t] += sm[t + s];
    __syncthreads();
  }
  if (t == 0) bsum[blockIdx.x] = sm[0];
}

__global__ void scan_bsum_kernel(int* __restrict__ bsum) {
  __shared__ int sm[1024];
  const int t = threadIdx.x;
  const int v = (t < NB) ? bsum[t] : 0;
  sm[t] = v;
  __syncthreads();
  for (int s = 1; s < 1024; s <<= 1) {
    const int a = (t >= s) ? sm[t - s] : 0;
    __syncthreads();
    sm[t] += a;
    __syncthreads();
  }
  if (t < NB) bsum[t] = sm[t] - v;   // exclusive
}

__global__ void scan_final_kernel(const int* __restrict__ cnt, const int* __restrict__ bsum,
                                  int* __restrict__ off, int* __restrict__ cur) {
  __shared__ int sm[256];
  const int t = threadIdx.x;
  const int g = blockIdx.x * 256 + t;
  const int v = cnt[g];
  sm[t] = v;
  __syncthreads();
  for (int s = 1; s < 256; s <<= 1) {
    const int a = (t >= s) ? sm[t - s] : 0;
    __syncthreads();
    sm[t] += a;
    __syncthreads();
  }
  const int ex = sm[t] - v + bsum[blockIdx.x];
  off[g] = ex;
  cur[g] = ex;
}

__global__ void reorder_kernel(const int* __restrict__ ei, const int* __restrict__ et,
                               int* __restrict__ cur, int* __restrict__ sorted_src) {
  const int e = blockIdx.x * 256 + threadIdx.x;
  const int seg = ei[N_EDGES + e] * NREL + et[e];
  const int pos = atomicAdd(&cur[seg], 1);
  sorted_src[pos] = ei[e];
}

// Fill Abf[:, 2048:2304] = bf16(x).  MUST run before aggregate (it gathers these).
__global__ void xcast_kernel(const float* __restrict__ x, unsigned short* __restrict__ abf) {
  const int id = blockIdx.x * 256 + threadIdx.x;   // 20000*64
  const int row = id >> 6, lane = id & 63;
  const float4 v = ((const float4*)x)[(size_t)row * 64 + lane];
  union { unsigned short u[4]; uint2 q; } pk;
  pk.u[0] = f2bf(v.x); pk.u[1] = f2bf(v.y);
  pk.u[2] = f2bf(v.z); pk.u[3] = f2bf(v.w);
  *(uint2*)(abf + (size_t)row * KTOT + KS + lane * 4) = pk.q;
}

// One wave per segment: gather bf16 x rows from Abf x-cols (8B/lane),
// f32-accumulate, write bf16 into Abf s-part.
__global__ void aggregate_kernel(const int* __restrict__ cnt, const int* __restrict__ off,
                                 const int* __restrict__ sorted_src,
                                 unsigned short* __restrict__ abf) {
  const int seg = __builtin_amdgcn_readfirstlane(blockIdx.x * 4 + (threadIdx.x >> 6));
  const int lane = threadIdx.x & 63;
  const int ne = cnt[seg];
  const int o  = off[seg];
  float a0 = 0.f, a1 = 0.f, a2 = 0.f, a3 = 0.f;
  float b0 = 0.f, b1 = 0.f, b2 = 0.f, b3 = 0.f;
  int j = 0;
  for (; j + 1 < ne; j += 2) {
    const int s0 = sorted_src[o + j];
    const int s1 = sorted_src[o + j + 1];
    const uint2 u0 = *(const uint2*)(abf + (size_t)s0 * KTOT + KS + lane * 4);
    const uint2 u1 = *(const uint2*)(abf + (size_t)s1 * KTOT + KS + lane * 4);
    a0 += bflo(u0.x); a1 += bfhi(u0.x); a2 += bflo(u0.y); a3 += bfhi(u0.y);
    b0 += bflo(u1.x); b1 += bfhi(u1.x); b2 += bflo(u1.y); b3 += bfhi(u1.y);
  }
  if (j < ne) {
    const uint2 u0 = *(const uint2*)(abf + (size_t)sorted_src[o + j] * KTOT + KS + lane * 4);
    a0 += bflo(u0.x); a1 += bfhi(u0.x); a2 += bflo(u0.y); a3 += bfhi(u0.y);
  }
  a0 += b0; a1 += b1; a2 += b2; a3 += b3;
  const int node = seg >> 3, r = seg & 7;
  union { unsigned short u[4]; uint2 q; } pk;
  pk.u[0] = f2bf(a0); pk.u[1] = f2bf(a1);
  pk.u[2] = f2bf(a2); pk.u[3] = f2bf(a3);
  *(uint2*)(abf + (size_t)node * KTOT + r * IN_DIM + lane * 4) = pk.q;
}

// WcatT[n][k], n in [0,896), k in [0,2304). n >= 800 zero-padded.
__global__ void build_wcat_kernel(const float* __restrict__ bases,
                                  const float* __restrict__ att,
                                  const float* __restrict__ root,
                                  unsigned short* __restrict__ wcatT) {
  const int k = blockIdx.x;
  const int n = blockIdx.y * 128 + threadIdx.x;
  float v = 0.f;
  if (n < OUT_DIM) {
    if (k < KS) {
      const int r = k >> 8, i = k & 255;
      #pragma unroll
      for (int b = 0; b < 8; ++b)
        v += att[r * 8 + b] * bases[((size_t)b * IN_DIM + i) * OUT_DIM + n];
    } else {
      v = root[(size_t)(k - KS) * OUT_DIM + n];
    }
  }
  wcatT[(size_t)n * KTOT + k] = f2bf(v);
}

// C[20000][800] = Abf[20000][2304] @ WcatT^T + bias.
// m97 structure: 128x128 tile, BK=64, 4 waves (2x2, 64x64), SINGLE 32KB LDS
// buffer, global_load_lds staging, plain __syncthreads (compiler drain),
// both-sides XOR swizzle (proven 0-conflict in r2/r3), ~3 blocks/CU overlap.
__global__ __launch_bounds__(256) void gemm_kernel(
    const unsigned short* __restrict__ abf,
    const unsigned short* __restrict__ wcatT,
    const float* __restrict__ bias, float* __restrict__ out) {
  __shared__ __align__(16) char lds[32768];        // A 16K | B 16K

  const int lin = blockIdx.x;
  const int q8 = NWG >> 3, r8 = NWG & 7;           // 137, 3
  const int xcd = lin & 7, idx = lin >> 3;
  const int wg = (xcd < r8 ? xcd * (q8 + 1) : r8 * (q8 + 1) + (xcd - r8) * q8) + idx;
  const int row0 = (wg % MT) * BM;
  const int col0 = (wg / MT) * BN;

  const int tid = threadIdx.x;
  const int w = tid >> 6, l = tid & 63;
  const int wm = w >> 1, wn = w & 1;               // wave tile: rows wm*64, cols wn*64
  const int la = l & 15, lg = l >> 4;
  const int l3 = l >> 3;
  const int sch = (l & 7) ^ l3;                    // pre-swizzled global k-chunk (T2)

  const unsigned short* gA[4];
  const unsigned short* gB[4];
  #pragma unroll
  for (int i = 0; i < 4; ++i) {
    const int r = i * 32 + w * 8 + l3;
    int ga = row0 + r;
    ga = (ga < N_NODES) ? ga : (N_NODES - 1);      // clamp: garbage rows never stored
    gA[i] = abf   + (size_t)ga * KTOT + sch * 8;
    gB[i] = wcatT + (size_t)(col0 + r) * KTOT + sch * 8;
  }
  char* const lA = lds + w * 1024;                 // HW adds lane*16
  char* const lB = lds + 16384 + w * 1024;

  f32x4_t acc[4][4];
  #pragma unroll
  for (int i = 0; i < 4; ++i)
    #pragma unroll
    for (int j = 0; j < 4; ++j)
      acc[i][j] = (f32x4_t)(0.0f);

  for (int kt = 0; kt < NKT; ++kt) {
    const int ko = kt * BK;
    #pragma unroll
    for (int i = 0; i < 4; ++i) {
      gload16(gA[i] + ko, lA + i * 4096);
      gload16(gB[i] + ko, lB + i * 4096);
    }
    __syncthreads();

    #pragma unroll
    for (int s = 0; s < 2; ++s) {
      short8_t af[4], bf[4];
      #pragma unroll
      for (int f = 0; f < 4; ++f) {
        const int rr = wm * 64 + f * 16 + la;
        af[f] = *(const short8_t*)(lds + rr * 128 +
                  (((s * 4 + lg) << 4) ^ ((rr & 7) << 4)));
      }
      #pragma unroll
      for (int nf = 0; nf < 4; ++nf) {
        const int rr = wn * 64 + nf * 16 + la;
        bf[nf] = *(const short8_t*)(lds + 16384 + rr * 128 +
                  (((s * 4 + lg) << 4) ^ ((rr & 7) << 4)));
      }
      #pragma unroll
      for (int f = 0; f < 4; ++f)
        #pragma unroll
        for (int nf = 0; nf < 4; ++nf)
          acc[f][nf] = __builtin_amdgcn_mfma_f32_16x16x32_bf16(
              af[f], bf[nf], acc[f][nf], 0, 0, 0);
    }
    __syncthreads();
  }

  #pragma unroll
  for (int nf = 0; nf < 4; ++nf) {
    const int gcol = col0 + wn * 64 + nf * 16 + la;
    if (gcol < OUT_DIM) {
      const float bv = bias[gcol];
      #pragma unroll
      for (int f = 0; f < 4; ++f) {
        const int gr0 = row0 + wm * 64 + f * 16 + lg * 4;
        #pragma unroll
        for (int j = 0; j < 4; ++j) {
          const int gr = gr0 + j;
          if (gr < N_NODES)
            out[(size_t)gr * OUT_DIM + gcol] = acc[f][nf][j] + bv;
        }
      }
    }
  }
}

extern "C" void kernel_launch(void* const* d_in, const int* in_sizes, int n_in,
                              void* d_out, int out_size, void* d_ws, size_t ws_size,
                              hipStream_t stream) {
  const float* x     = (const float*)d_in[0];
  const int*   ei    = (const int*)d_in[1];
  const int*   et    = (const int*)d_in[2];
  const float* bases = (const float*)d_in[3];
  const float* att   = (const float*)d_in[4];
  const float* root  = (const float*)d_in[5];
  const float* bias  = (const float*)d_in[6];
  float* out = (float*)d_out;

  char* p = (char*)d_ws;
  unsigned short* abf   = (unsigned short*)p;  p += (size_t)N_NODES * KTOT * 2;  // 92,160,000
  unsigned short* wcatT = (unsigned short*)p;  p += (size_t)NPAD * KTOT * 2;     //  4,128,768
  int* cnt        = (int*)p;                   p += (size_t)NSEG * 4;
  int* off        = (int*)p;                   p += (size_t)NSEG * 4;
  int* cur        = (int*)p;                   p += (size_t)NSEG * 4;
  int* sorted_src = (int*)p;                   p += (size_t)N_EDGES * 4;
  int* bsum       = (int*)p;                   p += 4096;

  zero_counts_kernel<<<NB, 256, 0, stream>>>(cnt);
  hist_kernel<<<N_EDGES / 256, 256, 0, stream>>>(ei, et, cnt);
  scan_reduce_kernel<<<NB, 256, 0, stream>>>(cnt, bsum);
  scan_bsum_kernel<<<1, 1024, 0, stream>>>(bsum);
  scan_final_kernel<<<NB, 256, 0, stream>>>(cnt, bsum, off, cur);
  reorder_kernel<<<N_EDGES / 256, 256, 0, stream>>>(ei, et, cur, sorted_src);
  xcast_kernel<<<N_NODES * 64 / 256, 256, 0, stream>>>(x, abf);     // before aggregate!
  aggregate_kernel<<<NSEG / 4, 256, 0, stream>>>(cnt, off, sorted_src, abf);
  build_wcat_kernel<<<dim3(KTOT, 7), 128, 0, stream>>>(bases, att, root, wcatT);
  gemm_kernel<<<NWG, 256, 0, stream>>>(abf, wcatT, bias, out);
}

// Round 6
// 269.384 us; speedup vs baseline: 2.7951x; 1.1249x over previous
//
#include <hip/hip_runtime.h>

// RGCNConv basis-decomposed, sort-based aggregation + 8-phase pipelined bf16 MFMA GEMM.
//   Abf = [seg_sum(bf16(x)[src] by (dst,rel)) | bf16(x)]  (bf16, [N][2304])
//   out = Abf @ WcatT^T + bias                            (f32 out)

#define N_NODES 20000
#define N_EDGES 640000
#define IN_DIM  256
#define OUT_DIM 800
#define NREL    8
#define NSEG    160000          // N_NODES * NREL
#define KS      2048            // NREL * IN_DIM
#define KTOT    2304            // KS + IN_DIM
#define NPAD    1024            // padded N for GEMM B (4 x 256)
#define NB      625             // NSEG / 256 scan blocks

// GEMM geometry: 128x256 tile, BK=64, 8 waves (2Mx4N, 64x64), triple-buffer LDS
#define BM 128
#define BN 256
#define BK 64
#define NKT (KTOT / BK)         // 36
#define MT  157                 // ceil(20000/128)
#define NT  4                   // 1024/256
#define NWG (MT * NT)           // 628
#define LBUF 49152              // per K-tile: A 16K | B 32K

typedef float f32x4_t __attribute__((ext_vector_type(4)));
typedef short short8_t __attribute__((ext_vector_type(8)));

__device__ __forceinline__ unsigned short f2bf(float f) {
  unsigned u = __float_as_uint(f);
  u += 0x7fffu + ((u >> 16) & 1u);
  return (unsigned short)(u >> 16);
}

__device__ __forceinline__ float bflo(unsigned w) { return __uint_as_float(w << 16); }
__device__ __forceinline__ float bfhi(unsigned w) { return __uint_as_float(w & 0xffff0000u); }

__device__ __forceinline__ void gload16(const void* g, void* l) {
  __builtin_amdgcn_global_load_lds(
      (const __attribute__((address_space(1))) void*)g,
      (__attribute__((address_space(3))) void*)l, 16, 0, 0);
}

// ---------------- sort pipeline ----------------

__global__ void zero_counts_kernel(int* __restrict__ cnt) {
  cnt[blockIdx.x * 256 + threadIdx.x] = 0;
}

__global__ void hist_kernel(const int* __restrict__ ei, const int* __restrict__ et,
                            int* __restrict__ cnt) {
  const int e = blockIdx.x * 256 + threadIdx.x;
  const int seg = ei[N_EDGES + e] * NREL + et[e];
  atomicAdd(&cnt[seg], 1);
}

__global__ void scan_reduce_kernel(const int* __restrict__ cnt, int* __restrict__ bsum) {
  __shared__ int sm[256];
  const int t = threadIdx.x;
  sm[t] = cnt[blockIdx.x * 256 + t];
  __syncthreads();
  for (int s = 128; s > 0; s >>= 1) {
    if (t < s) sm[t] += sm[t + s];
    __syncthreads();
  }
  if (t == 0) bsum[blockIdx.x] = sm[0];
}

__global__ void scan_bsum_kernel(int* __restrict__ bsum) {
  __shared__ int sm[1024];
  const int t = threadIdx.x;
  const int v = (t < NB) ? bsum[t] : 0;
  sm[t] = v;
  __syncthreads();
  for (int s = 1; s < 1024; s <<= 1) {
    const int a = (t >= s) ? sm[t - s] : 0;
    __syncthreads();
    sm[t] += a;
    __syncthreads();
  }
  if (t < NB) bsum[t] = sm[t] - v;   // exclusive
}

__global__ void scan_final_kernel(const int* __restrict__ cnt, const int* __restrict__ bsum,
                                  int* __restrict__ off, int* __restrict__ cur) {
  __shared__ int sm[256];
  const int t = threadIdx.x;
  const int g = blockIdx.x * 256 + t;
  const int v = cnt[g];
  sm[t] = v;
  __syncthreads();
  for (int s = 1; s < 256; s <<= 1) {
    const int a = (t >= s) ? sm[t - s] : 0;
    __syncthreads();
    sm[t] += a;
    __syncthreads();
  }
  const int ex = sm[t] - v + bsum[blockIdx.x];
  off[g] = ex;
  cur[g] = ex;
}

__global__ void reorder_kernel(const int* __restrict__ ei, const int* __restrict__ et,
                               int* __restrict__ cur, int* __restrict__ sorted_src) {
  const int e = blockIdx.x * 256 + threadIdx.x;
  const int seg = ei[N_EDGES + e] * NREL + et[e];
  const int pos = atomicAdd(&cur[seg], 1);
  sorted_src[pos] = ei[e];
}

// Fill Abf[:, 2048:2304] = bf16(x).  MUST run before aggregate (it gathers these).
__global__ void xcast_kernel(const float* __restrict__ x, unsigned short* __restrict__ abf) {
  const int id = blockIdx.x * 256 + threadIdx.x;   // 20000*64
  const int row = id >> 6, lane = id & 63;
  const float4 v = ((const float4*)x)[(size_t)row * 64 + lane];
  union { unsigned short u[4]; uint2 q; } pk;
  pk.u[0] = f2bf(v.x); pk.u[1] = f2bf(v.y);
  pk.u[2] = f2bf(v.z); pk.u[3] = f2bf(v.w);
  *(uint2*)(abf + (size_t)row * KTOT + KS + lane * 4) = pk.q;
}

// Two segments per wave (32 lanes each, uint4 = 16B/lane): gather bf16 x rows
// from Abf x-cols, f32-accumulate, write bf16 into Abf s-part.
__global__ void aggregate_kernel(const int* __restrict__ cnt, const int* __restrict__ off,
                                 const int* __restrict__ sorted_src,
                                 unsigned short* __restrict__ abf) {
  const int wv = blockIdx.x * 4 + (threadIdx.x >> 6);
  const int l = threadIdx.x & 63;
  const int seg = wv * 2 + (l >> 5);
  const int sl = l & 31;
  const int ne = cnt[seg];
  const int o  = off[seg];
  float a0 = 0.f, a1 = 0.f, a2 = 0.f, a3 = 0.f;
  float a4 = 0.f, a5 = 0.f, a6 = 0.f, a7 = 0.f;
  float c0 = 0.f, c1 = 0.f, c2 = 0.f, c3 = 0.f;
  float c4 = 0.f, c5 = 0.f, c6 = 0.f, c7 = 0.f;
  int j = 0;
  for (; j + 1 < ne; j += 2) {
    const int s0 = sorted_src[o + j];
    const int s1 = sorted_src[o + j + 1];
    const uint4 u = *(const uint4*)(abf + (size_t)s0 * KTOT + KS + sl * 8);
    const uint4 v = *(const uint4*)(abf + (size_t)s1 * KTOT + KS + sl * 8);
    a0 += bflo(u.x); a1 += bfhi(u.x); a2 += bflo(u.y); a3 += bfhi(u.y);
    a4 += bflo(u.z); a5 += bfhi(u.z); a6 += bflo(u.w); a7 += bfhi(u.w);
    c0 += bflo(v.x); c1 += bfhi(v.x); c2 += bflo(v.y); c3 += bfhi(v.y);
    c4 += bflo(v.z); c5 += bfhi(v.z); c6 += bflo(v.w); c7 += bfhi(v.w);
  }
  if (j < ne) {
    const uint4 u = *(const uint4*)(abf + (size_t)sorted_src[o + j] * KTOT + KS + sl * 8);
    a0 += bflo(u.x); a1 += bfhi(u.x); a2 += bflo(u.y); a3 += bfhi(u.y);
    a4 += bflo(u.z); a5 += bfhi(u.z); a6 += bflo(u.w); a7 += bfhi(u.w);
  }
  a0 += c0; a1 += c1; a2 += c2; a3 += c3;
  a4 += c4; a5 += c5; a6 += c6; a7 += c7;
  const int node = seg >> 3, r = seg & 7;
  union { unsigned short u[8]; uint4 q; } pk;
  pk.u[0] = f2bf(a0); pk.u[1] = f2bf(a1); pk.u[2] = f2bf(a2); pk.u[3] = f2bf(a3);
  pk.u[4] = f2bf(a4); pk.u[5] = f2bf(a5); pk.u[6] = f2bf(a6); pk.u[7] = f2bf(a7);
  *(uint4*)(abf + (size_t)node * KTOT + r * IN_DIM + sl * 8) = pk.q;
}

// WcatT[n][k], n in [0,1024), k in [0,2304). n >= 800 zero-padded.
__global__ void build_wcat_kernel(const float* __restrict__ bases,
                                  const float* __restrict__ att,
                                  const float* __restrict__ root,
                                  unsigned short* __restrict__ wcatT) {
  const int k = blockIdx.x;
  const int n = blockIdx.y * 128 + threadIdx.x;
  float v = 0.f;
  if (n < OUT_DIM) {
    if (k < KS) {
      const int r = k >> 8, i = k & 255;
      #pragma unroll
      for (int b = 0; b < 8; ++b)
        v += att[r * 8 + b] * bases[((size_t)b * IN_DIM + i) * OUT_DIM + n];
    } else {
      v = root[(size_t)(k - KS) * OUT_DIM + n];
    }
  }
  wcatT[(size_t)n * KTOT + k] = f2bf(v);
}

// C[20000][800] = Abf[20000][2304] @ WcatT^T + bias.
// 8-phase schedule (T3+T4+T5): 128x256, BK=64, 8 waves (2Mx4N, 64x64/wave),
// triple-buffered 144KB LDS, prefetch distance 2, one counted vmcnt(6)/K-tile,
// 4 phases/K-tile each {ds_read ∥ gload-issue ∥ barrier ∥ lgkmcnt ∥ 8 MFMA ∥ barrier},
// pre-swizzled-source XOR LDS scheme (r5-proven 0-conflict).
__global__ __launch_bounds__(512) void gemm_kernel(
    const unsigned short* __restrict__ abf,
    const unsigned short* __restrict__ wcatT,
    const float* __restrict__ bias, float* __restrict__ out) {
  __shared__ __align__(16) char lds[3 * LBUF];

  // T1: bijective XCD-chunk swizzle (m204); rows fastest within a chunk.
  const int lin = blockIdx.x;
  const int q8 = NWG >> 3, r8 = NWG & 7;           // 78, 4
  const int xcd = lin & 7, idx = lin >> 3;
  const int wg = (xcd < r8 ? xcd * (q8 + 1) : r8 * (q8 + 1) + (xcd - r8) * q8) + idx;
  const int row0 = (wg % MT) * BM;
  const int col0 = (wg / MT) * BN;

  const int tid = threadIdx.x;
  const int w = tid >> 6, l = tid & 63;
  const int wm = w >> 2, wn = w & 3;               // wave tile: rows wm*64, cols wn*64
  const int la = l & 15, lg = l >> 4;
  const int l3 = l >> 3;
  const int sch = (l & 7) ^ l3;                    // pre-swizzled global k-chunk (T2)

  // staging sources: A instr i covers rows i*64 + w*8 + l3; B instr i likewise.
  const unsigned short* gA[2];
  const unsigned short* gB[4];
  #pragma unroll
  for (int i = 0; i < 2; ++i) {
    int ga = row0 + i * 64 + w * 8 + l3;
    ga = (ga < N_NODES) ? ga : (N_NODES - 1);      // clamp: garbage rows never stored
    gA[i] = abf + (size_t)ga * KTOT + sch * 8;
  }
  #pragma unroll
  for (int i = 0; i < 4; ++i)
    gB[i] = wcatT + (size_t)(col0 + i * 64 + w * 8 + l3) * KTOT + sch * 8;

  f32x4_t acc[4][4];
  #pragma unroll
  for (int i = 0; i < 4; ++i)
    #pragma unroll
    for (int j = 0; j < 4; ++j)
      acc[i][j] = (f32x4_t)(0.0f);

  // full-tile stage (prologue only): 6 gload16 per thread
  auto stage_all = [&](int buf, int kt) {
    char* pA = lds + buf * LBUF + w * 1024;
    char* pB = pA + 16384;
    const int ko = kt * BK;
    gload16(gA[0] + ko, pA);
    gload16(gA[1] + ko, pA + 8192);
    gload16(gB[0] + ko, pB);
    gload16(gB[1] + ko, pB + 8192);
    gload16(gB[2] + ko, pB + 16384);
    gload16(gB[3] + ko, pB + 24576);
  };

  stage_all(0, 0);
  stage_all(1, 1);                                 // 12 loads in flight

  for (int kt = 0; kt < NKT; ++kt) {
    const int cbuf = kt % 3;
    const int pbuf = (kt + 2) % 3;
    const bool pf = (kt + 2) < NKT;
    const int pko = (kt + 2) * BK;
    const char* Ab = lds + cbuf * LBUF;
    const char* Bb = Ab + 16384;
    char* pA = lds + pbuf * LBUF + w * 1024;
    char* pB = pA + 16384;

    // entry: my 6 loads for this tile done; next tile's 6 stay in flight (T4)
    if (kt + 1 < NKT) { asm volatile("s_waitcnt vmcnt(6)" ::: "memory"); }
    else              { asm volatile("s_waitcnt vmcnt(0)" ::: "memory"); }
    __builtin_amdgcn_sched_barrier(0);
    __builtin_amdgcn_s_barrier();                  // all waves' staging visible

    short8_t af0, af1, bf0, bf1, bf2, bf3;

    // ---- phase 0: s=0, mf 0-1 (reads bf set for s=0) ----
    {
      const int r0 = wm * 64 + la,       r1 = wm * 64 + 16 + la;
      af0 = *(const short8_t*)(Ab + r0 * 128 + ((lg << 4) ^ ((r0 & 7) << 4)));
      af1 = *(const short8_t*)(Ab + r1 * 128 + ((lg << 4) ^ ((r1 & 7) << 4)));
      #pragma unroll
      for (int nf = 0; nf < 4; ++nf) {
        const int rr = wn * 64 + nf * 16 + la;
        const short8_t v = *(const short8_t*)(Bb + rr * 128 + ((lg << 4) ^ ((rr & 7) << 4)));
        if (nf == 0) bf0 = v; else if (nf == 1) bf1 = v; else if (nf == 2) bf2 = v; else bf3 = v;
      }
      if (pf) { gload16(gA[0] + pko, pA); gload16(gA[1] + pko, pA + 8192); }
      __builtin_amdgcn_s_barrier();
      asm volatile("s_waitcnt lgkmcnt(0)" ::: "memory");
      __builtin_amdgcn_sched_barrier(0);
      __builtin_amdgcn_s_setprio(1);
      acc[0][0] = __builtin_amdgcn_mfma_f32_16x16x32_bf16(af0, bf0, acc[0][0], 0, 0, 0);
      acc[0][1] = __builtin_amdgcn_mfma_f32_16x16x32_bf16(af0, bf1, acc[0][1], 0, 0, 0);
      acc[0][2] = __builtin_amdgcn_mfma_f32_16x16x32_bf16(af0, bf2, acc[0][2], 0, 0, 0);
      acc[0][3] = __builtin_amdgcn_mfma_f32_16x16x32_bf16(af0, bf3, acc[0][3], 0, 0, 0);
      acc[1][0] = __builtin_amdgcn_mfma_f32_16x16x32_bf16(af1, bf0, acc[1][0], 0, 0, 0);
      acc[1][1] = __builtin_amdgcn_mfma_f32_16x16x32_bf16(af1, bf1, acc[1][1], 0, 0, 0);
      acc[1][2] = __builtin_amdgcn_mfma_f32_16x16x32_bf16(af1, bf2, acc[1][2], 0, 0, 0);
      acc[1][3] = __builtin_amdgcn_mfma_f32_16x16x32_bf16(af1, bf3, acc[1][3], 0, 0, 0);
      __builtin_amdgcn_s_setprio(0);
      __builtin_amdgcn_s_barrier();
    }
    // ---- phase 1: s=0, mf 2-3 (reuse bf) ----
    {
      const int r0 = wm * 64 + 32 + la,  r1 = wm * 64 + 48 + la;
      af0 = *(const short8_t*)(Ab + r0 * 128 + ((lg << 4) ^ ((r0 & 7) << 4)));
      af1 = *(const short8_t*)(Ab + r1 * 128 + ((lg << 4) ^ ((r1 & 7) << 4)));
      if (pf) { gload16(gB[0] + pko, pB); gload16(gB[1] + pko, pB + 8192); }
      __builtin_amdgcn_s_barrier();
      asm volatile("s_waitcnt lgkmcnt(0)" ::: "memory");
      __builtin_amdgcn_sched_barrier(0);
      __builtin_amdgcn_s_setprio(1);
      acc[2][0] = __builtin_amdgcn_mfma_f32_16x16x32_bf16(af0, bf0, acc[2][0], 0, 0, 0);
      acc[2][1] = __builtin_amdgcn_mfma_f32_16x16x32_bf16(af0, bf1, acc[2][1], 0, 0, 0);
      acc[2][2] = __builtin_amdgcn_mfma_f32_16x16x32_bf16(af0, bf2, acc[2][2], 0, 0, 0);
      acc[2][3] = __builtin_amdgcn_mfma_f32_16x16x32_bf16(af0, bf3, acc[2][3], 0, 0, 0);
      acc[3][0] = __builtin_amdgcn_mfma_f32_16x16x32_bf16(af1, bf0, acc[3][0], 0, 0, 0);
      acc[3][1] = __builtin_amdgcn_mfma_f32_16x16x32_bf16(af1, bf1, acc[3][1], 0, 0, 0);
      acc[3][2] = __builtin_amdgcn_mfma_f32_16x16x32_bf16(af1, bf2, acc[3][2], 0, 0, 0);
      acc[3][3] = __builtin_amdgcn_mfma_f32_16x16x32_bf16(af1, bf3, acc[3][3], 0, 0, 0);
      __builtin_amdgcn_s_setprio(0);
      __builtin_amdgcn_s_barrier();
    }
    // ---- phase 2: s=1, mf 0-1 (reads bf set for s=1) ----
    {
      const int r0 = wm * 64 + la,       r1 = wm * 64 + 16 + la;
      af0 = *(const short8_t*)(Ab + r0 * 128 + (((4 + lg) << 4) ^ ((r0 & 7) << 4)));
      af1 = *(const short8_t*)(Ab + r1 * 128 + (((4 + lg) << 4) ^ ((r1 & 7) << 4)));
      #pragma unroll
      for (int nf = 0; nf < 4; ++nf) {
        const int rr = wn * 64 + nf * 16 + la;
        const short8_t v = *(const short8_t*)(Bb + rr * 128 + (((4 + lg) << 4) ^ ((rr & 7) << 4)));
        if (nf == 0) bf0 = v; else if (nf == 1) bf1 = v; else if (nf == 2) bf2 = v; else bf3 = v;
      }
      if (pf) { gload16(gB[2] + pko, pB + 16384); gload16(gB[3] + pko, pB + 24576); }
      __builtin_amdgcn_s_barrier();
      asm volatile("s_waitcnt lgkmcnt(0)" ::: "memory");
      __builtin_amdgcn_sched_barrier(0);
      __builtin_amdgcn_s_setprio(1);
      acc[0][0] = __builtin_amdgcn_mfma_f32_16x16x32_bf16(af0, bf0, acc[0][0], 0, 0, 0);
      acc[0][1] = __builtin_amdgcn_mfma_f32_16x16x32_bf16(af0, bf1, acc[0][1], 0, 0, 0);
      acc[0][2] = __builtin_amdgcn_mfma_f32_16x16x32_bf16(af0, bf2, acc[0][2], 0, 0, 0);
      acc[0][3] = __builtin_amdgcn_mfma_f32_16x16x32_bf16(af0, bf3, acc[0][3], 0, 0, 0);
      acc[1][0] = __builtin_amdgcn_mfma_f32_16x16x32_bf16(af1, bf0, acc[1][0], 0, 0, 0);
      acc[1][1] = __builtin_amdgcn_mfma_f32_16x16x32_bf16(af1, bf1, acc[1][1], 0, 0, 0);
      acc[1][2] = __builtin_amdgcn_mfma_f32_16x16x32_bf16(af1, bf2, acc[1][2], 0, 0, 0);
      acc[1][3] = __builtin_amdgcn_mfma_f32_16x16x32_bf16(af1, bf3, acc[1][3], 0, 0, 0);
      __builtin_amdgcn_s_setprio(0);
      __builtin_amdgcn_s_barrier();
    }
    // ---- phase 3: s=1, mf 2-3 (reuse bf; no issues) ----
    {
      const int r0 = wm * 64 + 32 + la,  r1 = wm * 64 + 48 + la;
      af0 = *(const short8_t*)(Ab + r0 * 128 + (((4 + lg) << 4) ^ ((r0 & 7) << 4)));
      af1 = *(const short8_t*)(Ab + r1 * 128 + (((4 + lg) << 4) ^ ((r1 & 7) << 4)));
      __builtin_amdgcn_s_barrier();
      asm volatile("s_waitcnt lgkmcnt(0)" ::: "memory");
      __builtin_amdgcn_sched_barrier(0);
      __builtin_amdgcn_s_setprio(1);
      acc[2][0] = __builtin_amdgcn_mfma_f32_16x16x32_bf16(af0, bf0, acc[2][0], 0, 0, 0);
      acc[2][1] = __builtin_amdgcn_mfma_f32_16x16x32_bf16(af0, bf1, acc[2][1], 0, 0, 0);
      acc[2][2] = __builtin_amdgcn_mfma_f32_16x16x32_bf16(af0, bf2, acc[2][2], 0, 0, 0);
      acc[2][3] = __builtin_amdgcn_mfma_f32_16x16x32_bf16(af0, bf3, acc[2][3], 0, 0, 0);
      acc[3][0] = __builtin_amdgcn_mfma_f32_16x16x32_bf16(af1, bf0, acc[3][0], 0, 0, 0);
      acc[3][1] = __builtin_amdgcn_mfma_f32_16x16x32_bf16(af1, bf1, acc[3][1], 0, 0, 0);
      acc[3][2] = __builtin_amdgcn_mfma_f32_16x16x32_bf16(af1, bf2, acc[3][2], 0, 0, 0);
      acc[3][3] = __builtin_amdgcn_mfma_f32_16x16x32_bf16(af1, bf3, acc[3][3], 0, 0, 0);
      __builtin_amdgcn_s_setprio(0);
      __builtin_amdgcn_s_barrier();
    }
  }

  #pragma unroll
  for (int nf = 0; nf < 4; ++nf) {
    const int gcol = col0 + wn * 64 + nf * 16 + la;
    if (gcol < OUT_DIM) {
      const float bv = bias[gcol];
      #pragma unroll
      for (int f = 0; f < 4; ++f) {
        const int gr0 = row0 + wm * 64 + f * 16 + lg * 4;
        #pragma unroll
        for (int j = 0; j < 4; ++j) {
          const int gr = gr0 + j;
          if (gr < N_NODES)
            out[(size_t)gr * OUT_DIM + gcol] = acc[f][nf][j] + bv;
        }
      }
    }
  }
}

extern "C" void kernel_launch(void* const* d_in, const int* in_sizes, int n_in,
                              void* d_out, int out_size, void* d_ws, size_t ws_size,
                              hipStream_t stream) {
  const float* x     = (const float*)d_in[0];
  const int*   ei    = (const int*)d_in[1];
  const int*   et    = (const int*)d_in[2];
  const float* bases = (const float*)d_in[3];
  const float* att   = (const float*)d_in[4];
  const float* root  = (const float*)d_in[5];
  const float* bias  = (const float*)d_in[6];
  float* out = (float*)d_out;

  char* p = (char*)d_ws;
  unsigned short* abf   = (unsigned short*)p;  p += (size_t)N_NODES * KTOT * 2;  // 92,160,000
  unsigned short* wcatT = (unsigned short*)p;  p += (size_t)NPAD * KTOT * 2;     //  4,718,592
  int* cnt        = (int*)p;                   p += (size_t)NSEG * 4;
  int* off        = (int*)p;                   p += (size_t)NSEG * 4;
  int* cur        = (int*)p;                   p += (size_t)NSEG * 4;
  int* sorted_src = (int*)p;                   p += (size_t)N_EDGES * 4;
  int* bsum       = (int*)p;                   p += 4096;

  zero_counts_kernel<<<NB, 256, 0, stream>>>(cnt);
  hist_kernel<<<N_EDGES / 256, 256, 0, stream>>>(ei, et, cnt);
  scan_reduce_kernel<<<NB, 256, 0, stream>>>(cnt, bsum);
  scan_bsum_kernel<<<1, 1024, 0, stream>>>(bsum);
  scan_final_kernel<<<NB, 256, 0, stream>>>(cnt, bsum, off, cur);
  reorder_kernel<<<N_EDGES / 256, 256, 0, stream>>>(ei, et, cur, sorted_src);
  xcast_kernel<<<N_NODES * 64 / 256, 256, 0, stream>>>(x, abf);     // before aggregate!
  aggregate_kernel<<<NSEG / 8, 256, 0, stream>>>(cnt, off, sorted_src, abf);
  build_wcat_kernel<<<dim3(KTOT, 8), 128, 0, stream>>>(bases, att, root, wcatT);
  gemm_kernel<<<NWG, 512, 0, stream>>>(abf, wcatT, bias, out);
}